// Round 2
// 268.578 us; speedup vs baseline: 1.0070x; 1.0070x over previous
//
#include <hip/hip_runtime.h>

// BasisEncoder: out[b, :] = one_hot(x[b] % 64, 64) as fp32.
// (x % 256) % 64 == x % 64 because 64 | 256; x >= 0 so & 63 is exact.
//
// Layout: out is row-major [B, 64] fp32 = [B, 16] float4.
// ILP=4 grid-stride: 4M threads, each issuing 4 independent
// load->compute->16B-NT-store chains at stride THREADS, so every
// store instruction is fully coalesced (16 consecutive lanes = one row,
// 64 lanes = 1 KiB contiguous) and each thread has 4 stores in flight.
//
// Note: __builtin_nontemporal_store requires a clang vector type, not
// HIP's float4 class -- use ext_vector_type(4).

typedef float f32x4 __attribute__((ext_vector_type(4)));

#define BATCH (1048576)
#define VEC_PER_ROW 16                   // 64 floats / 4
#define TOTAL_VEC (BATCH * VEC_PER_ROW)  // 16M float4 stores
#define ILP 4
#define THREADS (TOTAL_VEC / ILP)        // 4M threads
#define BLOCK 256
#define GRID (THREADS / BLOCK)           // 16384 blocks

__global__ __launch_bounds__(BLOCK) void basis_encoder_kernel(
    const int* __restrict__ x, f32x4* __restrict__ out) {
  const int gid0 = blockIdx.x * BLOCK + threadIdx.x;

  // Issue all 4 loads first (independent), then compute+store.
  unsigned idxs[ILP];
#pragma unroll
  for (int k = 0; k < ILP; ++k) {
    const int gid = gid0 + k * THREADS;
    const int row = gid >> 4;
    idxs[k] = (unsigned)x[row] & 63u;
  }

#pragma unroll
  for (int k = 0; k < ILP; ++k) {
    const int gid = gid0 + k * THREADS;
    const int base = (gid & 15) << 2;  // first column of this 4-col chunk
    const unsigned idx = idxs[k];
    f32x4 v;
    v.x = (idx == (unsigned)(base + 0)) ? 1.0f : 0.0f;
    v.y = (idx == (unsigned)(base + 1)) ? 1.0f : 0.0f;
    v.z = (idx == (unsigned)(base + 2)) ? 1.0f : 0.0f;
    v.w = (idx == (unsigned)(base + 3)) ? 1.0f : 0.0f;
    __builtin_nontemporal_store(v, &out[gid]);
  }
}

extern "C" void kernel_launch(void* const* d_in, const int* in_sizes, int n_in,
                              void* d_out, int out_size, void* d_ws, size_t ws_size,
                              hipStream_t stream) {
  const int* x = (const int*)d_in[0];
  f32x4* out = (f32x4*)d_out;
  basis_encoder_kernel<<<GRID, BLOCK, 0, stream>>>(x, out);
}